// Round 4
// baseline (268.812 us; speedup 1.0000x reference)
//
#include <hip/hip_runtime.h>
#include <math.h>

// Problem constants
#define B_    32
#define S_    2048
#define CIN_  256
#define COUT_ 256
#define K_    16
#define TOUT_ 2033   // S - K + 1
#define RTOT_ 4096   // CIN * K reduction length

typedef __bf16 bf16x4 __attribute__((ext_vector_type(4)));
typedef __bf16 bf16x8 __attribute__((ext_vector_type(8)));
typedef float  f32x16 __attribute__((ext_vector_type(16)));

#define GLOBAL_AS __attribute__((address_space(1)))
#define LDS_AS    __attribute__((address_space(3)))

__device__ __forceinline__ void gload_lds16(const void* g, void* l) {
  // async global -> LDS: per-lane global gather, LDS dest = wave-uniform base + lane*16
  __builtin_amdgcn_global_load_lds((const GLOBAL_AS void*)g, (LDS_AS void*)l, 16, 0, 0);
}

// ---------------------------------------------------------------------------
// Build w_eff in a FRAGMENT-MAJOR swizzled blob so that global_load_lds
// staging yields conflict-free (lane-sequential) B-fragment ds_read_b128s
// for v_mfma_f32_32x32x16_bf16.
//
// Element (o, i, kk), i = channel, reduction chunk c = kk*8 + (i>>5):
//   ob = o>>5 (8), s = (i>>4)&1, khalf = (i>>3)&1, olow = o&31, j = i&7
//   addr = ((c*8 + ob)*4 + s*2 + khalf)*256 + olow*8 + j            [2 MB total]
// Per chunk c: 16 KB; the nb half (ob = nb*4 ..+4) is 8 KB contiguous.
// B-frag (o5 = wn*2+jn, s): lane L reads 16 B at ((o5*4+s*2)*256) + L*16 B. ✓
// ---------------------------------------------------------------------------
__global__ void __launch_bounds__(256) build_wt_kernel(const float* __restrict__ wr,
                                                       const float* __restrict__ wi,
                                                       const float* __restrict__ ph,
                                                       __bf16* __restrict__ wt) {
  int t = blockIdx.x * 256 + threadIdx.x;   // one thread per (o,i)
  int o = t >> 8, i = t & 255;
  const float4* wr4 = (const float4*)(wr + (size_t)(o * CIN_ + i) * K_);
  const float4* wi4 = (const float4*)(wi + (size_t)(o * CIN_ + i) * K_);
  float re[16], im[16];
  #pragma unroll
  for (int v = 0; v < 4; v++) {
    float4 a = wr4[v];
    re[4*v+0]=a.x; re[4*v+1]=a.y; re[4*v+2]=a.z; re[4*v+3]=a.w;
    float4 b = wi4[v];
    im[4*v+0]=b.x; im[4*v+1]=b.y; im[4*v+2]=b.z; im[4*v+3]=b.w;
  }
  const int ob = o >> 5, s = (i >> 4) & 1, kh = (i >> 3) & 1;
  const int olow = o & 31, j = i & 7;
  const int ic = i >> 5;
  #pragma unroll
  for (int kk = 0; kk < K_; kk++) {
    float p = ph[kk];
    int c = kk * 8 + ic;
    int addr = (((c * 8 + ob) * 4 + s * 2 + kh) * 256) + olow * 8 + j;
    wt[addr] = (__bf16)(cosf(p)*re[kk] - sinf(p)*im[kk]);
  }
}

// ---------------------------------------------------------------------------
// Main: implicit-GEMM conv, 32x32x16 bf16 MFMA, tap-resident A tile.
// Block = 256 threads (4 waves, 2x2 wave grid), C-tile 128x128 (t x o),
// wave tile 64x64 = 2x2 of 32x32; BK=32 -> 8 MFMAs/iter/wave.
// As: fragment-major bf16 [plane p = i_local>>3][row 0..143][j 0..7],
//     plane stride 145 rows -> frag reads lane-sequential (conflict-free).
// Bs: 8 KB staged via global_load_lds from the pre-swizzled wt blob ->
//     frag reads at Bs + group*1KB + lane*16 (conflict-free).
// ---------------------------------------------------------------------------
__global__ void __launch_bounds__(256) conv_mfma_kernel(const float* __restrict__ xg,
                                                        const __bf16* __restrict__ wt,
                                                        float* __restrict__ out) {
  __shared__ __align__(16) __bf16 As[4 * 145 * 8];  // 9280 B
  __shared__ __align__(16) __bf16 Bs[4096];         // 8 KB

  const int bx = blockIdx.x;
  const int nb = bx & 1;          // o-block 0..1
  const int mb = (bx >> 1) & 15;  // t-block 0..15
  const int b  = bx >> 5;         // batch   0..31

  const int tid  = threadIdx.x;
  const int w    = tid >> 6;
  const int lane = tid & 63;
  const int wm   = w >> 1, wn = w & 1;
  const int l31  = lane & 31, lhi = lane >> 5;

  const int t0 = mb * 128;
  const int o0 = nb * 128;

  const float*  xbase  = xg + (size_t)b * (S_ * CIN_);
  const __bf16* wtbase = wt + nb * 4096;   // + c*8192 per chunk

  // A staging geometry: thread -> (row sr, 4 fp32 at channel sc)
  const int sr = tid >> 3;        // 0..31
  const int sc = (tid & 7) * 4;   // 0,4,...,28
  const int sp = sc >> 3;         // frag plane
  const int sj = sc & 7;          // 0 or 4 within 8-elem block

  f32x16 acc[2][2];
  #pragma unroll
  for (int jm = 0; jm < 2; jm++)
    #pragma unroll
    for (int jn = 0; jn < 2; jn++)
      #pragma unroll
      for (int r = 0; r < 16; r++)
        acc[jm][jn][r] = 0.f;

  for (int ic = 0; ic < 8; ++ic) {
    const int i0 = ic * 32;

    __syncthreads();  // previous ic's As reads + previous kk's Bs reads done

    // ---- Stage A: x rows t0..t0+143 (clamped), channels i0..i0+32 ----
    {
      const float* xcol = xbase + i0 + sc;
      #pragma unroll
      for (int p = 0; p < 4; p++) {
        int r = p * 32 + sr;
        int rg = t0 + r; rg = (rg < S_) ? rg : (S_ - 1);
        float4 v = *(const float4*)(xcol + (size_t)rg * CIN_);
        bf16x4 o4; o4[0]=(__bf16)v.x; o4[1]=(__bf16)v.y; o4[2]=(__bf16)v.z; o4[3]=(__bf16)v.w;
        *(bf16x4*)(As + (sp * 145 + r) * 8 + sj) = o4;
      }
      if (tid < 128) {  // tail rows 128..143
        int r = 128 + sr;
        int rg = t0 + r; rg = (rg < S_) ? rg : (S_ - 1);
        float4 v = *(const float4*)(xcol + (size_t)rg * CIN_);
        bf16x4 o4; o4[0]=(__bf16)v.x; o4[1]=(__bf16)v.y; o4[2]=(__bf16)v.z; o4[3]=(__bf16)v.w;
        *(bf16x4*)(As + (sp * 145 + r) * 8 + sj) = o4;
      }
    }

    for (int kk = 0; kk < K_; ++kk) {
      if (kk) __syncthreads();  // previous kk's Bs reads done

      // ---- Stage B: swizzled chunk c = kk*8+ic, nb half = 8 KB ----
      const __bf16* gb = wtbase + (size_t)(kk * 8 + ic) * 8192;
      #pragma unroll
      for (int p = 0; p < 2; p++) {
        int seg = w * 2 + p;  // 8 segments of 512 elems (1 KB)
        gload_lds16(gb + seg * 512 + lane * 8, (void*)(Bs + seg * 512));
      }

      __syncthreads();  // drains lgkm (A writes, first iter) + vmcnt (B)

      // ---- Fragments ----
      // A[m = l31][k = lhi*8+j] at plane p = s*2+lhi, row = kk + m_tile + l31
      bf16x8 af[2][2], bfr[2][2];
      #pragma unroll
      for (int jm = 0; jm < 2; jm++)
        #pragma unroll
        for (int s = 0; s < 2; s++) {
          int row = kk + wm * 64 + jm * 32 + l31;
          af[jm][s] = *(const bf16x8*)(As + ((s * 2 + lhi) * 145 + row) * 8);
        }
      #pragma unroll
      for (int jn = 0; jn < 2; jn++)
        #pragma unroll
        for (int s = 0; s < 2; s++) {
          int grp = (wn * 2 + jn) * 4 + s * 2 + lhi;
          bfr[jn][s] = *(const bf16x8*)(Bs + grp * 256 + l31 * 8);
        }

      #pragma unroll
      for (int s = 0; s < 2; s++)
        #pragma unroll
        for (int jm = 0; jm < 2; jm++)
          #pragma unroll
          for (int jn = 0; jn < 2; jn++)
            acc[jm][jn] = __builtin_amdgcn_mfma_f32_32x32x16_bf16(af[jm][s], bfr[jn][s], acc[jm][jn], 0, 0, 0);
    }
  }

  // ---- Epilogue: 32x32 C/D: col = l31, row = (reg&3) + 8*(reg>>2) + 4*lhi ----
  float* obase = out + (size_t)b * TOUT_ * COUT_;
  #pragma unroll
  for (int jm = 0; jm < 2; jm++) {
    #pragma unroll
    for (int reg = 0; reg < 16; reg++) {
      int rowcd = (reg & 3) + 8 * (reg >> 2) + 4 * lhi;
      int t = t0 + wm * 64 + jm * 32 + rowcd;
      if (t < TOUT_) {
        float* orow = obase + (size_t)t * COUT_ + o0 + wn * 64 + l31;
        #pragma unroll
        for (int jn = 0; jn < 2; jn++)
          orow[jn * 32] = acc[jm][jn][reg];
      }
    }
  }
}

// ---------------------------------------------------------------------------
extern "C" void kernel_launch(void* const* d_in, const int* in_sizes, int n_in,
                              void* d_out, int out_size, void* d_ws, size_t ws_size,
                              hipStream_t stream) {
  const float* x  = (const float*)d_in[0];
  const float* wr = (const float*)d_in[1];
  const float* wi = (const float*)d_in[2];
  const float* ph = (const float*)d_in[3];
  float* out = (float*)d_out;

  __bf16* wt = (__bf16*)d_ws;  // 2 MB only

  build_wt_kernel<<<dim3((COUT_ * CIN_) / 256), dim3(256), 0, stream>>>(wr, wi, ph, wt);
  conv_mfma_kernel<<<dim3(B_ * 16 * 2), dim3(256), 0, stream>>>(x, wt, out);
}

// Round 5
// 237.396 us; speedup vs baseline: 1.1323x; 1.1323x over previous
//
#include <hip/hip_runtime.h>
#include <math.h>

// Problem constants
#define B_    32
#define S_    2048
#define CIN_  256
#define COUT_ 256
#define K_    16
#define TOUT_ 2033   // S - K + 1

typedef __bf16 bf16x4 __attribute__((ext_vector_type(4)));
typedef __bf16 bf16x8 __attribute__((ext_vector_type(8)));
typedef float  f32x4  __attribute__((ext_vector_type(4)));

// ---------------------------------------------------------------------------
// Build w_eff as a FRAGMENT-MAJOR blob for direct global->register B loads
// with v_mfma_f32_16x16x32_bf16.
// Element (o, i, kk): chunk = kk*8 + (i>>5); og = o>>4; q = (i>>3)&3;
//   n = o&15; j = i&7.
//   elem addr = chunk*8192 + og*512 + q*128 + n*8 + j        [2 MB total]
// Wave-read for o-group og, lane L = q*16+n: 16 B at chunk*8192+og*512 + L*8
// -> one fully-coalesced 1 KB global_load_dwordx4 per fragment. Verified-
// equivalent content to R3's B^T tiles (same (o, i) -> (k'=q*8+j) pairing).
// ---------------------------------------------------------------------------
__global__ void __launch_bounds__(256) build_wt_kernel(const float* __restrict__ wr,
                                                       const float* __restrict__ wi,
                                                       const float* __restrict__ ph,
                                                       __bf16* __restrict__ wt) {
  int t = blockIdx.x * 256 + threadIdx.x;   // one thread per (o,i)
  int o = t >> 8, i = t & 255;
  const float4* wr4 = (const float4*)(wr + (size_t)(o * CIN_ + i) * K_);
  const float4* wi4 = (const float4*)(wi + (size_t)(o * CIN_ + i) * K_);
  float re[16], im[16];
  #pragma unroll
  for (int v = 0; v < 4; v++) {
    float4 a = wr4[v];
    re[4*v+0]=a.x; re[4*v+1]=a.y; re[4*v+2]=a.z; re[4*v+3]=a.w;
    float4 b = wi4[v];
    im[4*v+0]=b.x; im[4*v+1]=b.y; im[4*v+2]=b.z; im[4*v+3]=b.w;
  }
  const int og = o >> 4, n = o & 15;
  const int ic = i >> 5, q = (i >> 3) & 3, j = i & 7;
  #pragma unroll
  for (int kk = 0; kk < K_; kk++) {
    float p = ph[kk];
    int chunk = kk * 8 + ic;
    wt[(size_t)chunk * 8192 + og * 512 + q * 128 + n * 8 + j]
        = (__bf16)(cosf(p)*re[kk] - sinf(p)*im[kk]);
  }
}

// ---------------------------------------------------------------------------
// Main: implicit-GEMM conv, 16x16x32 bf16 MFMA, barrier-free inner loop.
// Block = 256 threads (4 waves, 2x2), C-tile 128x128 (t x o).
// A: x rows t0..t0+143, 32 ch, in LDS padded [144][36] bf16 (conflict-free
//    fragment reads), restaged per ic (8x) via register round-trip -> only
//    16 barriers per block.
// B: loaded global->register from the fragment-major wt blob (L2-resident),
//    one-interval register prefetch (bnext while computing bcur) -> the
//    kk-loop has NO barriers and no vmcnt(0) drains (AITER-style pipeline).
// ---------------------------------------------------------------------------
#define AROW 36  // padded LDS row stride (elems): word stride 18 -> 2-way max

__global__ void __launch_bounds__(256) conv_mfma_kernel(const float* __restrict__ xg,
                                                        const __bf16* __restrict__ wt,
                                                        float* __restrict__ out) {
  __shared__ __align__(16) __bf16 As[144 * AROW];  // 10368 B

  const int bx = blockIdx.x;
  const int nb = bx & 1;          // o-block 0..1
  const int mb = (bx >> 1) & 15;  // t-block 0..15
  const int b  = bx >> 5;         // batch   0..31

  const int tid  = threadIdx.x;
  const int w    = tid >> 6;
  const int lane = tid & 63;
  const int wm   = w >> 1, wn = w & 1;
  const int n16  = lane & 15, q = lane >> 4;

  const int t0 = mb * 128;
  const int o0 = nb * 128;

  const float* xbase = xg + (size_t)b * (S_ * CIN_);

  // B fragment global bases: og = nb*8 + wn*4 + jn, + lane*8 elems
  const __bf16* wfrag = wt + (size_t)(nb * 8 + wn * 4) * 512 + lane * 8;

  // A staging geometry: thread -> (row sr, 4 fp32 at channel sc)
  const int sr = tid >> 3;        // 0..31
  const int sc = (tid & 7) * 4;   // 0,4,...,28

  f32x4 acc[4][4];
  #pragma unroll
  for (int im_ = 0; im_ < 4; im_++)
    #pragma unroll
    for (int in_ = 0; in_ < 4; in_++)
      acc[im_][in_] = {0.f, 0.f, 0.f, 0.f};

  // Preload B fragments for global interval 0 (chunk 0).
  bf16x8 bcur[4], bnext[4];
  #pragma unroll
  for (int jn = 0; jn < 4; jn++)
    bcur[jn] = *(const bf16x8*)(wfrag + (size_t)jn * 512);

  for (int ic = 0; ic < 8; ++ic) {
    const int i0 = ic * 32;

    __syncthreads();  // previous ic's As reads done (per-wave waitcnt precedes barrier)

    // ---- Stage A: x rows t0..t0+143 (clamped), channels i0..i0+32 ----
    {
      const float* xcol = xbase + i0 + sc;
      #pragma unroll
      for (int p = 0; p < 4; p++) {
        int r = p * 32 + sr;
        int rg = t0 + r; rg = (rg < S_) ? rg : (S_ - 1);
        float4 v = *(const float4*)(xcol + (size_t)rg * CIN_);
        bf16x4 o4; o4[0]=(__bf16)v.x; o4[1]=(__bf16)v.y; o4[2]=(__bf16)v.z; o4[3]=(__bf16)v.w;
        *(bf16x4*)(As + r * AROW + sc) = o4;
      }
      if (tid < 128) {  // tail rows 128..143
        int r = 128 + sr;
        int rg = t0 + r; rg = (rg < S_) ? rg : (S_ - 1);
        float4 v = *(const float4*)(xcol + (size_t)rg * CIN_);
        bf16x4 o4; o4[0]=(__bf16)v.x; o4[1]=(__bf16)v.y; o4[2]=(__bf16)v.z; o4[3]=(__bf16)v.w;
        *(bf16x4*)(As + r * AROW + sc) = o4;
      }
    }

    __syncthreads();  // As(ic) visible

    for (int kk = 0; kk < K_; ++kk) {
      // ---- Prefetch next interval's B fragments (global, L2-hot) ----
      int g  = ic * 16 + kk;
      int gn = (g < 127) ? g + 1 : 127;
      int chunk_n = ((gn & 15) << 3) + (gn >> 4);
      #pragma unroll
      for (int jn = 0; jn < 4; jn++)
        bnext[jn] = *(const bf16x8*)(wfrag + (size_t)chunk_n * 8192 + (size_t)jn * 512);

      // ---- A fragments (LDS, conflict-free) ----
      bf16x8 af[4];
      #pragma unroll
      for (int jm = 0; jm < 4; jm++) {
        int row = kk + wm * 64 + jm * 16 + n16;    // A[m=lane&15][k=q*8+j]
        af[jm] = *(const bf16x8*)(As + row * AROW + q * 8);
      }

      // ---- 16 MFMAs on bcur (no waits on bnext) ----
      #pragma unroll
      for (int jm = 0; jm < 4; jm++)
        #pragma unroll
        for (int jn = 0; jn < 4; jn++)
          acc[jm][jn] = __builtin_amdgcn_mfma_f32_16x16x32_bf16(af[jm], bcur[jn], acc[jm][jn], 0, 0, 0);

      #pragma unroll
      for (int jn = 0; jn < 4; jn++)
        bcur[jn] = bnext[jn];
    }
  }

  // ---- Epilogue: C/D layout col = lane&15, row = (lane>>4)*4 + reg ----
  float* obase = out + (size_t)b * TOUT_ * COUT_;
  #pragma unroll
  for (int jm = 0; jm < 4; jm++) {
    #pragma unroll
    for (int r = 0; r < 4; r++) {
      int t = t0 + wm * 64 + jm * 16 + q * 4 + r;
      if (t < TOUT_) {
        float* orow = obase + (size_t)t * COUT_ + o0 + wn * 64 + n16;
        #pragma unroll
        for (int jn = 0; jn < 4; jn++)
          orow[jn * 16] = acc[jm][jn][r];
      }
    }
  }
}

// ---------------------------------------------------------------------------
extern "C" void kernel_launch(void* const* d_in, const int* in_sizes, int n_in,
                              void* d_out, int out_size, void* d_ws, size_t ws_size,
                              hipStream_t stream) {
  const float* x  = (const float*)d_in[0];
  const float* wr = (const float*)d_in[1];
  const float* wi = (const float*)d_in[2];
  const float* ph = (const float*)d_in[3];
  float* out = (float*)d_out;

  __bf16* wt = (__bf16*)d_ws;  // 2 MB only

  build_wt_kernel<<<dim3((COUT_ * CIN_) / 256), dim3(256), 0, stream>>>(wr, wi, ph, wt);
  conv_mfma_kernel<<<dim3(B_ * 16 * 2), dim3(256), 0, stream>>>(x, wt, out);
}